// Round 4
// baseline (197.687 us; speedup 1.0000x reference)
//
#include <hip/hip_runtime.h>

#define B_    16
#define T_    4096
#define D_    1024
#define CD_   8
#define CS_   1024
#define NROWS 65536
#define EPSF  1e-12f
#define RPB   64          // rows per block

// ---- d_out float offsets (outputs concatenated flat in return order) ----
#define OUT_OFF    0           // [16,4096,1024] = 67108864
#define COMMIT_OFF 67108864    // [16]
#define CBLOSS_OFF 67108880    // [16]
#define IDX_OFF    67108896    // [16,4096] as float
#define ZE_OFF     67174432    // [16,4096,8]

// ---------------------------------------------------------------------------
// Zero the 32 loss accumulators (atomics accumulate; replays need fresh zeros)
// ---------------------------------------------------------------------------
__global__ __launch_bounds__(64)
void vq_zero(float* __restrict__ dout) {
    int t = threadIdx.x;
    if (t < 32) dout[COMMIT_OFF + t] = 0.f;
}

// ---------------------------------------------------------------------------
// Fully fused VQ: per block of 64 rows:
//   P0: build in_wT in LDS (weight-norm, same fp sequence as before)
//   P1: z_e GEMV (bit-identical), write z_e global + LDS
//   P2: rebuild LDS with normalized codebook; 8-thread/row scan (first-max)
//   P3: rebuild LDS with out_w; out projection + losses
// ---------------------------------------------------------------------------
__global__ __launch_bounds__(512)
void vq_fused(const float* __restrict__ z,
              const float* __restrict__ in_v, const float* __restrict__ in_g,
              const float* __restrict__ in_b,
              const float* __restrict__ out_v, const float* __restrict__ out_g,
              const float* __restrict__ out_b,
              const float* __restrict__ cb, float* __restrict__ dout) {
    __shared__ float s_main[CD_ * D_];   // 32 KB: in_wT -> cbn(row-major) -> out_w
    __shared__ float s_cn2[CS_];         // 4 KB
    __shared__ float s_ze[RPB * CD_];    // 2 KB
    __shared__ int   s_idx[RPB];         // 256 B
    __shared__ float s_norm[CD_];
    __shared__ float s_loss[8];

    int t = threadIdx.x;
    int lane = t & 63;
    int wid = t >> 6;                    // 0..7
    int base = blockIdx.x * RPB;

    // ---- P0: column norms of in_v (wave w handles column w; identical math) ----
    {
        float s = 0.f;
        #pragma unroll
        for (int i = 0; i < D_ / 64; ++i) {
            float v = in_v[(size_t)(lane + 64 * i) * CD_ + wid];
            s = fmaf(v, v, s);
        }
        #pragma unroll
        for (int m = 1; m <= 32; m <<= 1) s += __shfl_xor(s, m, 64);
        if (lane == 0) s_norm[wid] = sqrtf(s);
    }
    __syncthreads();
    #pragma unroll
    for (int rep = 0; rep < (CD_ * D_) / 512; ++rep) {
        int idx = rep * 512 + t;
        int c = idx >> 10, d = idx & (D_ - 1);
        s_main[idx] = in_g[c] * in_v[(size_t)d * CD_ + c] / fmaxf(EPSF, s_norm[c]);
    }
    __syncthreads();

    // ---- P1: z_e GEMV, 4 iters x (8 waves x 2 rows) = 64 rows ----
    float bia[CD_];
    #pragma unroll
    for (int c = 0; c < CD_; ++c) bia[c] = in_b[c];

    for (int itr = 0; itr < 4; ++itr) {
        int lrow = itr * 16 + wid * 2;
        int row0 = base + lrow;

        float ze[2][CD_];
        #pragma unroll
        for (int r = 0; r < 2; ++r)
            #pragma unroll
            for (int c = 0; c < CD_; ++c) ze[r][c] = 0.f;

        #pragma unroll
        for (int k = 0; k < 4; ++k) {
            float4 zv0 = *(const float4*)(z + (size_t)(row0)     * D_ + (k << 8) + (lane << 2));
            float4 zv1 = *(const float4*)(z + (size_t)(row0 + 1) * D_ + (k << 8) + (lane << 2));
            #pragma unroll
            for (int c = 0; c < CD_; ++c) {
                float4 w4 = *(const float4*)(s_main + c * D_ + (k << 8) + (lane << 2));
                ze[0][c] = fmaf(zv0.x, w4.x, ze[0][c]);
                ze[0][c] = fmaf(zv0.y, w4.y, ze[0][c]);
                ze[0][c] = fmaf(zv0.z, w4.z, ze[0][c]);
                ze[0][c] = fmaf(zv0.w, w4.w, ze[0][c]);
                ze[1][c] = fmaf(zv1.x, w4.x, ze[1][c]);
                ze[1][c] = fmaf(zv1.y, w4.y, ze[1][c]);
                ze[1][c] = fmaf(zv1.z, w4.z, ze[1][c]);
                ze[1][c] = fmaf(zv1.w, w4.w, ze[1][c]);
            }
        }

        #pragma unroll
        for (int r = 0; r < 2; ++r) {
            #pragma unroll
            for (int c = 0; c < CD_; ++c) {
                float v = ze[r][c];
                v += __shfl_xor(v, 1, 64);
                v += __shfl_xor(v, 2, 64);
                v += __shfl_xor(v, 4, 64);
                v += __shfl_xor(v, 8, 64);
                v += __shfl_xor(v, 16, 64);
                v += __shfl_xor(v, 32, 64);
                ze[r][c] = v + bia[c];
            }
        }

        if (lane == 0) {
            float4 p0 = make_float4(ze[0][0], ze[0][1], ze[0][2], ze[0][3]);
            float4 p1 = make_float4(ze[0][4], ze[0][5], ze[0][6], ze[0][7]);
            *(float4*)(dout + ZE_OFF + (size_t)row0 * CD_)     = p0;
            *(float4*)(dout + ZE_OFF + (size_t)row0 * CD_ + 4) = p1;
            *(float4*)(s_ze + lrow * CD_)     = p0;
            *(float4*)(s_ze + lrow * CD_ + 4) = p1;
        }
        if (lane == 1) {
            float4 p0 = make_float4(ze[1][0], ze[1][1], ze[1][2], ze[1][3]);
            float4 p1 = make_float4(ze[1][4], ze[1][5], ze[1][6], ze[1][7]);
            *(float4*)(dout + ZE_OFF + (size_t)(row0 + 1) * CD_)     = p0;
            *(float4*)(dout + ZE_OFF + (size_t)(row0 + 1) * CD_ + 4) = p1;
            *(float4*)(s_ze + (lrow + 1) * CD_)     = p0;
            *(float4*)(s_ze + (lrow + 1) * CD_ + 4) = p1;
        }
    }
    __syncthreads();

    // ---- P2a: rebuild s_main with normalized codebook (row-major) + cn2 ----
    #pragma unroll
    for (int rep = 0; rep < 2; ++rep) {
        int j = rep * 512 + t;
        float v[CD_]; float s = 0.f;
        #pragma unroll
        for (int c = 0; c < CD_; ++c) { v[c] = cb[j * CD_ + c]; s = fmaf(v[c], v[c], s); }
        float n = fmaxf(EPSF, sqrtf(s));
        float n2 = 0.f;
        #pragma unroll
        for (int c = 0; c < CD_; ++c) {
            float q = v[c] / n;
            s_main[j * CD_ + c] = q;
            n2 = fmaf(q, q, n2);
        }
        s_cn2[j] = n2;
    }
    __syncthreads();

    // ---- P2b: scan. 8 threads per row, interleaved codes j = jj*8+sub ----
    int r = t >> 3;
    int sub = t & 7;
    {
        float4 a  = *(const float4*)(s_ze + r * CD_);
        float4 b4 = *(const float4*)(s_ze + r * CD_ + 4);

        float s = 0.f;
        s = fmaf(a.x, a.x, s);  s = fmaf(a.y, a.y, s);
        s = fmaf(a.z, a.z, s);  s = fmaf(a.w, a.w, s);
        s = fmaf(b4.x, b4.x, s); s = fmaf(b4.y, b4.y, s);
        s = fmaf(b4.z, b4.z, s); s = fmaf(b4.w, b4.w, s);
        float tw = 2.f / fmaxf(EPSF, sqrtf(s));

        float bs = -1e38f;
        int bj = 0;
        #pragma unroll 4
        for (int jj = 0; jj < 128; ++jj) {
            int j = (jj << 3) + sub;
            float4 ca  = ((const float4*)s_main)[j * 2];
            float4 cbv = ((const float4*)s_main)[j * 2 + 1];
            float dot = 0.f;
            dot = fmaf(ca.x,  a.x,  dot);
            dot = fmaf(ca.y,  a.y,  dot);
            dot = fmaf(ca.z,  a.z,  dot);
            dot = fmaf(ca.w,  a.w,  dot);
            dot = fmaf(cbv.x, b4.x, dot);
            dot = fmaf(cbv.y, b4.y, dot);
            dot = fmaf(cbv.z, b4.z, dot);
            dot = fmaf(cbv.w, b4.w, dot);
            float sc = fmaf(dot, tw, -s_cn2[j]);
            if (sc > bs || (sc == bs && j < bj)) { bs = sc; bj = j; }
        }
        // reduce across the 8 sub-threads (lanes sub=0..7 adjacent)
        #pragma unroll
        for (int m = 1; m <= 4; m <<= 1) {
            float os = __shfl_xor(bs, m, 64);
            int   oj = __shfl_xor(bj, m, 64);
            bool take = (os > bs) || (os == bs && oj < bj);
            bs = take ? os : bs;
            bj = take ? oj : bj;
        }

        // losses: (z_e - cb[bj])^2; only sub==0 contributes, wave-reduce
        float lsum = 0.f;
        if (sub == 0) {
            const float* q = cb + (size_t)bj * CD_;
            float d0 = a.x  - q[0]; lsum = fmaf(d0, d0, lsum);
            float d1 = a.y  - q[1]; lsum = fmaf(d1, d1, lsum);
            float d2 = a.z  - q[2]; lsum = fmaf(d2, d2, lsum);
            float d3 = a.w  - q[3]; lsum = fmaf(d3, d3, lsum);
            float d4 = b4.x - q[4]; lsum = fmaf(d4, d4, lsum);
            float d5 = b4.y - q[5]; lsum = fmaf(d5, d5, lsum);
            float d6 = b4.z - q[6]; lsum = fmaf(d6, d6, lsum);
            float d7 = b4.w - q[7]; lsum = fmaf(d7, d7, lsum);
        }
        lsum += __shfl_xor(lsum, 1, 64);
        lsum += __shfl_xor(lsum, 2, 64);
        lsum += __shfl_xor(lsum, 4, 64);
        lsum += __shfl_xor(lsum, 8, 64);
        lsum += __shfl_xor(lsum, 16, 64);
        lsum += __shfl_xor(lsum, 32, 64);
        if (lane == 0) s_loss[wid] = lsum;

        if (sub == 0) {
            s_idx[r] = bj;
            dout[IDX_OFF + base + r] = (float)bj;
        }
    }
    __syncthreads();

    if (t == 0) {
        float tot = 0.f;
        #pragma unroll
        for (int w = 0; w < 8; ++w) tot += s_loss[w];
        float v = tot * (1.f / 32768.f);
        int bt = base >> 12;
        atomicAdd(dout + COMMIT_OFF + bt, v);
        atomicAdd(dout + CBLOSS_OFF + bt, v);
    }

    // ---- P3a: rebuild s_main with out_w (c-major; identical math) ----
    #pragma unroll
    for (int rep = 0; rep < 2; ++rep) {
        int d = rep * 512 + t;
        float v[CD_]; float s = 0.f;
        #pragma unroll
        for (int c = 0; c < CD_; ++c) { v[c] = out_v[c * D_ + d]; s = fmaf(v[c], v[c], s); }
        float n = fmaxf(EPSF, sqrtf(s));
        float g = out_g[d];
        #pragma unroll
        for (int c = 0; c < CD_; ++c) s_main[c * D_ + d] = g * v[c] / n;
    }
    __syncthreads();

    // ---- P3b: out projection: 2 iters x (8 waves x 4 rows) = 64 rows ----
    float4 ob[4];
    #pragma unroll
    for (int k = 0; k < 4; ++k)
        ob[k] = *(const float4*)(out_b + (k << 8) + (lane << 2));

    for (int itr = 0; itr < 2; ++itr) {
        int lr0 = itr * 32 + wid * 4;
        int row0 = base + lr0;

        float zq[4][CD_];
        #pragma unroll
        for (int rr = 0; rr < 4; ++rr) {
            int j = s_idx[lr0 + rr];
            #pragma unroll
            for (int c = 0; c < CD_; ++c) zq[rr][c] = cb[j * CD_ + c];
        }

        #pragma unroll
        for (int k = 0; k < 4; ++k) {
            float4 a0 = ob[k], a1 = ob[k], a2 = ob[k], a3 = ob[k];
            #pragma unroll
            for (int c = 0; c < CD_; ++c) {
                float4 w4 = *(const float4*)(s_main + c * D_ + (k << 8) + (lane << 2));
                a0.x = fmaf(zq[0][c], w4.x, a0.x); a0.y = fmaf(zq[0][c], w4.y, a0.y);
                a0.z = fmaf(zq[0][c], w4.z, a0.z); a0.w = fmaf(zq[0][c], w4.w, a0.w);
                a1.x = fmaf(zq[1][c], w4.x, a1.x); a1.y = fmaf(zq[1][c], w4.y, a1.y);
                a1.z = fmaf(zq[1][c], w4.z, a1.z); a1.w = fmaf(zq[1][c], w4.w, a1.w);
                a2.x = fmaf(zq[2][c], w4.x, a2.x); a2.y = fmaf(zq[2][c], w4.y, a2.y);
                a2.z = fmaf(zq[2][c], w4.z, a2.z); a2.w = fmaf(zq[2][c], w4.w, a2.w);
                a3.x = fmaf(zq[3][c], w4.x, a3.x); a3.y = fmaf(zq[3][c], w4.y, a3.y);
                a3.z = fmaf(zq[3][c], w4.z, a3.z); a3.w = fmaf(zq[3][c], w4.w, a3.w);
            }
            size_t obase = (size_t)row0 * D_ + (k << 8) + (lane << 2);
            *(float4*)(dout + OUT_OFF + obase)           = a0;
            *(float4*)(dout + OUT_OFF + obase + D_)      = a1;
            *(float4*)(dout + OUT_OFF + obase + 2 * D_)  = a2;
            *(float4*)(dout + OUT_OFF + obase + 3 * D_)  = a3;
        }
    }
}

extern "C" void kernel_launch(void* const* d_in, const int* in_sizes, int n_in,
                              void* d_out, int out_size, void* d_ws, size_t ws_size,
                              hipStream_t stream) {
    const float* z     = (const float*)d_in[0];
    const float* in_v  = (const float*)d_in[1];
    const float* in_g  = (const float*)d_in[2];
    const float* in_b  = (const float*)d_in[3];
    const float* out_v = (const float*)d_in[4];
    const float* out_g = (const float*)d_in[5];
    const float* out_b = (const float*)d_in[6];
    const float* cb    = (const float*)d_in[7];
    float* dout = (float*)d_out;

    vq_zero<<<1, 64, 0, stream>>>(dout);
    vq_fused<<<NROWS / RPB, 512, 0, stream>>>(z, in_v, in_g, in_b,
                                              out_v, out_g, out_b, cb, dout);
}

// Round 5
// 179.514 us; speedup vs baseline: 1.1012x; 1.1012x over previous
//
#include <hip/hip_runtime.h>

#define B_    16
#define T_    4096
#define D_    1024
#define CD_   8
#define CS_   1024
#define NROWS 65536
#define EPSF  1e-12f

// ---- d_out float offsets (outputs concatenated flat in return order) ----
#define OUT_OFF    0           // [16,4096,1024] = 67108864
#define COMMIT_OFF 67108864    // [16]
#define CBLOSS_OFF 67108880    // [16]
#define IDX_OFF    67108896    // [16,4096] as float
#define ZE_OFF     67174432    // [16,4096,8]

// ---- ws float offsets ----
#define WS_INWT 0        // in_wT   [8][1024]  (c-major)
#define WS_CBR  8192     // cbn_row [1024][8]  (row-major normalized codebook)
#define WS_OUTW 16384    // out_w   [8][1024]  (c-major)
#define WS_CN2  24576    // ||cbn_j||^2 [1024]
#define WS_IDX  25600    // indices as int [65536]

// ---------------------------------------------------------------------------
// Prep, parallelized to 24 blocks x 256:
//  blocks 0..15 : in_wT slice (each block redundantly computes the 8 column
//                 norms with the SAME per-column fp sequence as before)
//  blocks 16..19: normalized codebook rows (256 j each)
//  blocks 20..23: out_w (256 d each)
//  block 0 also zeros the 32 loss accumulators.
// ---------------------------------------------------------------------------
__global__ __launch_bounds__(256)
void vq_prep(const float* __restrict__ in_v, const float* __restrict__ in_g,
             const float* __restrict__ out_v, const float* __restrict__ out_g,
             const float* __restrict__ cb, float* __restrict__ ws,
             float* __restrict__ dout) {
    int t = threadIdx.x;
    int blk = blockIdx.x;

    if (blk < 16) {
        // ---- column norms of in_v: wave w handles cols w and w+4 ----
        __shared__ float s_norm[CD_];
        int lane = t & 63;
        int wid = t >> 6;     // 0..3
        #pragma unroll
        for (int half = 0; half < 2; ++half) {
            int c = wid + half * 4;
            float s = 0.f;
            #pragma unroll
            for (int i = 0; i < D_ / 64; ++i) {
                float v = in_v[(size_t)(lane + 64 * i) * CD_ + c];
                s = fmaf(v, v, s);
            }
            #pragma unroll
            for (int m = 1; m <= 32; m <<= 1) s += __shfl_xor(s, m, 64);
            if (lane == 0) s_norm[c] = sqrtf(s);
        }
        __syncthreads();

        // write this block's 512-element slice of in_wT
        #pragma unroll
        for (int rep = 0; rep < 2; ++rep) {
            int idx = blk * 512 + rep * 256 + t;
            int c = idx >> 10, d = idx & (D_ - 1);
            ws[WS_INWT + idx] = in_g[c] * in_v[(size_t)d * CD_ + c] / fmaxf(EPSF, s_norm[c]);
        }

        if (blk == 0 && t < 32) dout[COMMIT_OFF + t] = 0.f;
    } else if (blk < 20) {
        // ---- normalized codebook rows ----
        int j = (blk - 16) * 256 + t;
        float v[CD_]; float s = 0.f;
        #pragma unroll
        for (int c = 0; c < CD_; ++c) { v[c] = cb[j * CD_ + c]; s = fmaf(v[c], v[c], s); }
        float n = fmaxf(EPSF, sqrtf(s));
        float n2 = 0.f;
        #pragma unroll
        for (int c = 0; c < CD_; ++c) {
            float q = v[c] / n;
            ws[WS_CBR + j * CD_ + c] = q;
            n2 = fmaf(q, q, n2);
        }
        ws[WS_CN2 + j] = n2;
    } else {
        // ---- out_w ----
        int d = (blk - 20) * 256 + t;
        float v[CD_]; float s = 0.f;
        #pragma unroll
        for (int c = 0; c < CD_; ++c) { v[c] = out_v[c * D_ + d]; s = fmaf(v[c], v[c], s); }
        float n = fmaxf(EPSF, sqrtf(s));
        float g = out_g[d];
        #pragma unroll
        for (int c = 0; c < CD_; ++c) ws[WS_OUTW + c * D_ + d] = g * v[c] / n;
    }
}

// ---------------------------------------------------------------------------
// Stage 1: z_e = z @ in_wT + in_b. Pure streaming GEMV (bit-identical math).
// ---------------------------------------------------------------------------
__global__ __launch_bounds__(256)
void vq_ze(const float* __restrict__ z, const float* __restrict__ in_b,
           const float* __restrict__ ws, float* __restrict__ dout) {
    __shared__ float lds[CD_ * D_];  // in_wT, 32 KB
    int t = threadIdx.x;
    #pragma unroll
    for (int i = 0; i < 8; ++i)
        ((float4*)lds)[i * 256 + t] = ((const float4*)ws)[i * 256 + t];
    __syncthreads();

    int lane = t & 63;
    int wv = (blockIdx.x << 2) + (t >> 6);  // 0..8191

    float bia[CD_];
    #pragma unroll
    for (int c = 0; c < CD_; ++c) bia[c] = in_b[c];

    for (int it = 0; it < 4; ++it) {
        int bi = wv + (it << 13);   // 0..32767
        int row0 = bi << 1;         // 2 consecutive rows

        float ze[2][CD_];
        #pragma unroll
        for (int r = 0; r < 2; ++r)
            #pragma unroll
            for (int c = 0; c < CD_; ++c) ze[r][c] = 0.f;

        #pragma unroll
        for (int k = 0; k < 4; ++k) {
            float4 zv0 = *(const float4*)(z + (size_t)(row0)     * D_ + (k << 8) + (lane << 2));
            float4 zv1 = *(const float4*)(z + (size_t)(row0 + 1) * D_ + (k << 8) + (lane << 2));
            #pragma unroll
            for (int c = 0; c < CD_; ++c) {
                float4 w4 = *(const float4*)(lds + c * D_ + (k << 8) + (lane << 2));
                ze[0][c] = fmaf(zv0.x, w4.x, ze[0][c]);
                ze[0][c] = fmaf(zv0.y, w4.y, ze[0][c]);
                ze[0][c] = fmaf(zv0.z, w4.z, ze[0][c]);
                ze[0][c] = fmaf(zv0.w, w4.w, ze[0][c]);
                ze[1][c] = fmaf(zv1.x, w4.x, ze[1][c]);
                ze[1][c] = fmaf(zv1.y, w4.y, ze[1][c]);
                ze[1][c] = fmaf(zv1.z, w4.z, ze[1][c]);
                ze[1][c] = fmaf(zv1.w, w4.w, ze[1][c]);
            }
        }

        #pragma unroll
        for (int r = 0; r < 2; ++r) {
            #pragma unroll
            for (int c = 0; c < CD_; ++c) {
                float v = ze[r][c];
                v += __shfl_xor(v, 1, 64);
                v += __shfl_xor(v, 2, 64);
                v += __shfl_xor(v, 4, 64);
                v += __shfl_xor(v, 8, 64);
                v += __shfl_xor(v, 16, 64);
                v += __shfl_xor(v, 32, 64);
                ze[r][c] = v + bia[c];
            }
        }

        if (lane == 0) {
            *(float4*)(dout + ZE_OFF + (size_t)row0 * CD_) =
                make_float4(ze[0][0], ze[0][1], ze[0][2], ze[0][3]);
            *(float4*)(dout + ZE_OFF + (size_t)row0 * CD_ + 4) =
                make_float4(ze[0][4], ze[0][5], ze[0][6], ze[0][7]);
        }
        if (lane == 1) {
            *(float4*)(dout + ZE_OFF + (size_t)(row0 + 1) * CD_) =
                make_float4(ze[1][0], ze[1][1], ze[1][2], ze[1][3]);
            *(float4*)(dout + ZE_OFF + (size_t)(row0 + 1) * CD_ + 4) =
                make_float4(ze[1][4], ze[1][5], ze[1][6], ze[1][7]);
        }
    }
}

// ---------------------------------------------------------------------------
// Stage 2: scan. 32 rows per block, 8 threads per row (round-4 P2b structure,
// bit-exact scores, first-max tie policy). 2048 blocks -> 8 blocks/CU.
// ---------------------------------------------------------------------------
__global__ __launch_bounds__(256)
void vq_scan(const float* __restrict__ ze_in, const float* __restrict__ cb,
             const float* __restrict__ ws, float* __restrict__ dout,
             int* __restrict__ idx_out) {
    __shared__ float s_cb[CS_ * CD_];  // 32 KB
    __shared__ float s_c2[CS_];        // 4 KB
    __shared__ float s_loss[4];
    int t = threadIdx.x;
    #pragma unroll
    for (int i = 0; i < 8; ++i)
        ((float4*)s_cb)[i * 256 + t] = ((const float4*)(ws + WS_CBR))[i * 256 + t];
    ((float4*)s_c2)[t] = ((const float4*)(ws + WS_CN2))[t];
    __syncthreads();

    int lane = t & 63;
    int wid = t >> 6;
    int r = t >> 3;            // 0..31 local row
    int sub = t & 7;
    int row = blockIdx.x * 32 + r;

    float4 a  = *(const float4*)(ze_in + (size_t)row * CD_);
    float4 b4 = *(const float4*)(ze_in + (size_t)row * CD_ + 4);

    float s = 0.f;
    s = fmaf(a.x, a.x, s);   s = fmaf(a.y, a.y, s);
    s = fmaf(a.z, a.z, s);   s = fmaf(a.w, a.w, s);
    s = fmaf(b4.x, b4.x, s); s = fmaf(b4.y, b4.y, s);
    s = fmaf(b4.z, b4.z, s); s = fmaf(b4.w, b4.w, s);
    float tw = 2.f / fmaxf(EPSF, sqrtf(s));

    float bs = -1e38f;
    int bj = 0;
    #pragma unroll 4
    for (int jj = 0; jj < 128; ++jj) {
        int j = (jj << 3) + sub;
        float4 ca  = ((const float4*)s_cb)[j * 2];
        float4 cbv = ((const float4*)s_cb)[j * 2 + 1];
        float dot = 0.f;
        dot = fmaf(ca.x,  a.x,  dot);
        dot = fmaf(ca.y,  a.y,  dot);
        dot = fmaf(ca.z,  a.z,  dot);
        dot = fmaf(ca.w,  a.w,  dot);
        dot = fmaf(cbv.x, b4.x, dot);
        dot = fmaf(cbv.y, b4.y, dot);
        dot = fmaf(cbv.z, b4.z, dot);
        dot = fmaf(cbv.w, b4.w, dot);
        float sc = fmaf(dot, tw, -s_c2[j]);
        if (sc > bs || (sc == bs && j < bj)) { bs = sc; bj = j; }
    }
    // reduce across the 8 sub-threads
    #pragma unroll
    for (int m = 1; m <= 4; m <<= 1) {
        float os = __shfl_xor(bs, m, 64);
        int   oj = __shfl_xor(bj, m, 64);
        bool take = (os > bs) || (os == bs && oj < bj);
        bs = take ? os : bs;
        bj = take ? oj : bj;
    }

    // losses: only sub==0 contributes, then full-wave butterfly
    float lsum = 0.f;
    if (sub == 0) {
        const float* q = cb + (size_t)bj * CD_;
        float d0 = a.x  - q[0]; lsum = fmaf(d0, d0, lsum);
        float d1 = a.y  - q[1]; lsum = fmaf(d1, d1, lsum);
        float d2 = a.z  - q[2]; lsum = fmaf(d2, d2, lsum);
        float d3 = a.w  - q[3]; lsum = fmaf(d3, d3, lsum);
        float d4 = b4.x - q[4]; lsum = fmaf(d4, d4, lsum);
        float d5 = b4.y - q[5]; lsum = fmaf(d5, d5, lsum);
        float d6 = b4.z - q[6]; lsum = fmaf(d6, d6, lsum);
        float d7 = b4.w - q[7]; lsum = fmaf(d7, d7, lsum);
    }
    lsum += __shfl_xor(lsum, 1, 64);
    lsum += __shfl_xor(lsum, 2, 64);
    lsum += __shfl_xor(lsum, 4, 64);
    lsum += __shfl_xor(lsum, 8, 64);
    lsum += __shfl_xor(lsum, 16, 64);
    lsum += __shfl_xor(lsum, 32, 64);
    if (lane == 0) s_loss[wid] = lsum;

    if (sub == 0) {
        dout[IDX_OFF + row] = (float)bj;
        idx_out[row] = bj;
    }
    __syncthreads();
    if (t == 0) {
        float tot = s_loss[0] + s_loss[1] + s_loss[2] + s_loss[3];
        float v = tot * (1.f / 32768.f);
        int bt = row >> 12;
        atomicAdd(dout + COMMIT_OFF + bt, v);
        atomicAdd(dout + CBLOSS_OFF + bt, v);
    }
}

// ---------------------------------------------------------------------------
// Out projection: out = codebook[idx] @ out_w + out_b   (write-bound)
// ---------------------------------------------------------------------------
__global__ __launch_bounds__(256)
void vq_out(const float* __restrict__ cb, const float* __restrict__ ws,
            const float* __restrict__ out_b, const int* __restrict__ idx,
            float* __restrict__ out) {
    int t = threadIdx.x;
    int lane = t & 63;
    int wv = (blockIdx.x << 2) + (t >> 6);  // 0..4095
    const float* ow = ws + WS_OUTW;

    float4 ob[4];
    #pragma unroll
    for (int k = 0; k < 4; ++k)
        ob[k] = *(const float4*)(out_b + (k << 8) + (lane << 2));

    for (int it = 0; it < 4; ++it) {
        int bi = wv + (it << 12);
        int row0 = bi << 2;

        float zq[4][CD_];
        #pragma unroll
        for (int r = 0; r < 4; ++r) {
            int j = idx[row0 + r];
            #pragma unroll
            for (int c = 0; c < CD_; ++c) zq[r][c] = cb[j * CD_ + c];
        }

        #pragma unroll
        for (int k = 0; k < 4; ++k) {
            float4 a0 = ob[k], a1 = ob[k], a2 = ob[k], a3 = ob[k];
            #pragma unroll
            for (int c = 0; c < CD_; ++c) {
                float4 w4 = *(const float4*)(ow + c * D_ + (k << 8) + (lane << 2));
                a0.x = fmaf(zq[0][c], w4.x, a0.x); a0.y = fmaf(zq[0][c], w4.y, a0.y);
                a0.z = fmaf(zq[0][c], w4.z, a0.z); a0.w = fmaf(zq[0][c], w4.w, a0.w);
                a1.x = fmaf(zq[1][c], w4.x, a1.x); a1.y = fmaf(zq[1][c], w4.y, a1.y);
                a1.z = fmaf(zq[1][c], w4.z, a1.z); a1.w = fmaf(zq[1][c], w4.w, a1.w);
                a2.x = fmaf(zq[2][c], w4.x, a2.x); a2.y = fmaf(zq[2][c], w4.y, a2.y);
                a2.z = fmaf(zq[2][c], w4.z, a2.z); a2.w = fmaf(zq[2][c], w4.w, a2.w);
                a3.x = fmaf(zq[3][c], w4.x, a3.x); a3.y = fmaf(zq[3][c], w4.y, a3.y);
                a3.z = fmaf(zq[3][c], w4.z, a3.z); a3.w = fmaf(zq[3][c], w4.w, a3.w);
            }
            size_t base = (size_t)row0 * D_ + (k << 8) + (lane << 2);
            *(float4*)(out + base)            = a0;
            *(float4*)(out + base + D_)       = a1;
            *(float4*)(out + base + 2 * D_)   = a2;
            *(float4*)(out + base + 3 * D_)   = a3;
        }
    }
}

extern "C" void kernel_launch(void* const* d_in, const int* in_sizes, int n_in,
                              void* d_out, int out_size, void* d_ws, size_t ws_size,
                              hipStream_t stream) {
    const float* z     = (const float*)d_in[0];
    const float* in_v  = (const float*)d_in[1];
    const float* in_g  = (const float*)d_in[2];
    const float* in_b  = (const float*)d_in[3];
    const float* out_v = (const float*)d_in[4];
    const float* out_g = (const float*)d_in[5];
    const float* out_b = (const float*)d_in[6];
    const float* cb    = (const float*)d_in[7];
    float* dout = (float*)d_out;
    float* ws   = (float*)d_ws;
    int* idxp   = (int*)(ws + WS_IDX);

    vq_prep<<<24, 256, 0, stream>>>(in_v, in_g, out_v, out_g, cb, ws, dout);
    vq_ze<<<2048, 256, 0, stream>>>(z, in_b, ws, dout);
    vq_scan<<<2048, 256, 0, stream>>>(dout + ZE_OFF, cb, ws, dout, idxp);
    vq_out<<<1024, 256, 0, stream>>>(cb, ws, out_b, idxp, dout + OUT_OFF);
}